// Round 1
// baseline (903.078 us; speedup 1.0000x reference)
//
#include <hip/hip_runtime.h>

#define BATCH 4
#define CCH   64
#define NPIX  4096
#define KD    32
#define OD    64
#define KK    409       // N / TOPK
#define EPSF  1e-10f

__device__ __forceinline__ unsigned int fkey(float f) {
    unsigned int b = __float_as_uint(f);
    // monotonic float->uint transform (ascending order)
    return b ^ ((b & 0x80000000u) ? 0xFFFFFFFFu : 0x80000000u);
}

// ---------------------------------------------------------------------------
// Kernel A: per-pixel linear projections (1x1 convs).
//   Q  [B][N][KD]   (row contiguous per pixel)
//   Km [B][KD][N]   (n contiguous -> coalesced energy loop)
//   Vm [B][N][OD]   (transposed: v contiguous per pixel -> coalesced PV gather)
// ---------------------------------------------------------------------------
__global__ __launch_bounds__(256) void qkv_kernel(
    const float* __restrict__ x,
    const float* __restrict__ Wq, const float* __restrict__ bq,
    const float* __restrict__ Wk, const float* __restrict__ bk,
    const float* __restrict__ Wv, const float* __restrict__ bv,
    float* __restrict__ Q, float* __restrict__ Km, float* __restrict__ Vm)
{
    __shared__ float xt[64][65];
    __shared__ float wq_s[KD * 64];
    __shared__ float wk_s[KD * 64];
    __shared__ float wv_s[OD * 64];
    __shared__ float bq_s[KD], bk_s[KD], bv_s[OD];

    int tid = threadIdx.x;
    int bx  = blockIdx.x;
    int b   = bx >> 6;            // 64 tiles of 64 pixels per batch
    int n0  = (bx & 63) << 6;

    for (int i = tid; i < KD * 64; i += 256) { wq_s[i] = Wq[i]; wk_s[i] = Wk[i]; }
    for (int i = tid; i < OD * 64; i += 256) wv_s[i] = Wv[i];
    if (tid < KD) { bq_s[tid] = bq[tid]; bk_s[tid] = bk[tid]; }
    if (tid < OD) bv_s[tid] = bv[tid];
    for (int i = tid; i < 64 * 64; i += 256) {
        int c = i >> 6, p = i & 63;
        xt[c][p] = x[((size_t)b * CCH + c) * NPIX + n0 + p];
    }
    __syncthreads();

    int px  = tid & 63;
    int grp = tid >> 6;
    int n   = n0 + px;

    if (grp == 0) {
        for (int o = 0; o < KD; ++o) {
            float acc = bq_s[o];
            #pragma unroll
            for (int c = 0; c < 64; ++c) acc += wq_s[o * 64 + c] * xt[c][px];
            Q[((size_t)b * NPIX + n) * KD + o] = acc;
        }
    } else if (grp == 1) {
        for (int o = 0; o < KD; ++o) {
            float acc = bk_s[o];
            #pragma unroll
            for (int c = 0; c < 64; ++c) acc += wk_s[o * 64 + c] * xt[c][px];
            Km[((size_t)b * KD + o) * NPIX + n] = acc;
        }
    } else {
        int obase = (grp - 2) * 32;
        for (int oo = 0; oo < 32; ++oo) {
            int o = obase + oo;
            float acc = bv_s[o];
            #pragma unroll
            for (int c = 0; c < 64; ++c) acc += wv_s[o * 64 + c] * xt[c][px];
            Vm[((size_t)b * NPIX + n) * OD + o] = acc;
        }
    }
}

// ---------------------------------------------------------------------------
// Kernel B: one block per output row i (B*N blocks, 256 threads).
//   energy row -> LDS; block max; exact radix-select of 409th largest;
//   compact selected (j, exp) pairs; PV gather; fused residual epilogue.
// ---------------------------------------------------------------------------
__global__ __launch_bounds__(256) void attn_kernel(
    const float* __restrict__ x,  const float* __restrict__ Q,
    const float* __restrict__ Km, const float* __restrict__ Vm,
    const float* __restrict__ gamma, float* __restrict__ out)
{
    __shared__ float e[NPIX];                 // 16 KB energy row
    __shared__ float qs[KD];
    __shared__ unsigned int hist[256];
    __shared__ float red[4];
    __shared__ int   sel_idx[KK + 8];
    __shared__ float sel_w[KK + 8];
    __shared__ float pv[256];
    __shared__ unsigned int sh_prefix, sh_r, sh_nsel, sh_neq;
    __shared__ float sh_m;

    int tid = threadIdx.x;
    int bx  = blockIdx.x;
    int b   = bx >> 12;            // / 4096
    int i   = bx & (NPIX - 1);

    if (tid < KD) qs[tid] = Q[((size_t)b * NPIX + i) * KD + tid];
    if (tid == 0) { sh_nsel = 0u; sh_neq = 0u; }
    __syncthreads();

    // ---- energy row + local max ----
    const float* Kb = Km + (size_t)b * KD * NPIX;
    float lmax = -1e30f;
    for (int j = tid; j < NPIX; j += 256) {
        float acc = 0.f;
        #pragma unroll
        for (int kd = 0; kd < KD; ++kd) acc += qs[kd] * Kb[kd * NPIX + j];
        e[j] = acc;
        lmax = fmaxf(lmax, acc);
    }
    for (int off = 32; off; off >>= 1) lmax = fmaxf(lmax, __shfl_down(lmax, off, 64));
    if ((tid & 63) == 0) red[tid >> 6] = lmax;
    __syncthreads();
    if (tid == 0) sh_m = fmaxf(fmaxf(red[0], red[1]), fmaxf(red[2], red[3]));
    __syncthreads();
    float m = sh_m;

    // ---- exact radix select: key of the KK-th largest element ----
    unsigned int prefix = 0u, kmask = 0u, r = KK;
    for (int pass = 0; pass < 4; ++pass) {
        int shift = 24 - 8 * pass;
        hist[tid] = 0u;
        __syncthreads();
        for (int j = tid; j < NPIX; j += 256) {
            unsigned int u = fkey(e[j]);
            if ((u & kmask) == prefix) atomicAdd(&hist[(u >> shift) & 255u], 1u);
        }
        __syncthreads();
        if (tid == 0) {
            unsigned int cum = 0u;
            for (int d = 255; d >= 0; --d) {
                unsigned int c = hist[d];
                if (cum + c >= r) {
                    sh_prefix = prefix | ((unsigned int)d << shift);
                    sh_r = r - cum;
                    break;
                }
                cum += c;
            }
        }
        __syncthreads();
        prefix = sh_prefix;
        r      = sh_r;
        kmask |= 0xFFu << shift;
        __syncthreads();
    }
    unsigned int tu = prefix;      // exact key of KK-th largest; r = #equals to keep

    // ---- selection + weights ----
    float lsum = 0.f;
    for (int j = tid; j < NPIX; j += 256) {
        unsigned int u = fkey(e[j]);
        bool sel = (u > tu);
        if (!sel && u == tu) {
            unsigned int p = atomicAdd(&sh_neq, 1u);
            sel = (p < r);
        }
        if (sel) {
            float w = __expf(e[j] - m);
            unsigned int p = atomicAdd(&sh_nsel, 1u);
            sel_idx[p] = j;
            sel_w[p]   = w;
            lsum += w;
        }
    }
    __syncthreads();
    for (int off = 32; off; off >>= 1) lsum += __shfl_down(lsum, off, 64);
    if ((tid & 63) == 0) red[tid >> 6] = lsum;
    __syncthreads();
    float denom = (red[0] + red[1] + red[2] + red[3]) + EPSF;
    int nsel = (int)sh_nsel;

    // ---- PV gather: out[v] = sum_sel w * V[j][v] ----
    int v = tid & 63, g = tid >> 6;
    const float* Vb = Vm + (size_t)b * NPIX * OD;
    float acc = 0.f;
    for (int s = g; s < nsel; s += 4) {
        acc += sel_w[s] * Vb[(size_t)sel_idx[s] * OD + v];
    }
    pv[tid] = acc;
    __syncthreads();
    if (tid < 64) {
        float o = pv[tid] + pv[tid + 64] + pv[tid + 128] + pv[tid + 192];
        float scale = gamma[0] / denom;
        size_t oi = ((size_t)b * CCH + tid) * NPIX + i;
        out[oi] = scale * o + x[oi];
    }
}

extern "C" void kernel_launch(void* const* d_in, const int* in_sizes, int n_in,
                              void* d_out, int out_size, void* d_ws, size_t ws_size,
                              hipStream_t stream) {
    const float* x     = (const float*)d_in[0];
    const float* Wq    = (const float*)d_in[1];
    const float* bq    = (const float*)d_in[2];
    const float* Wk    = (const float*)d_in[3];
    const float* bk    = (const float*)d_in[4];
    const float* Wv    = (const float*)d_in[5];
    const float* bv    = (const float*)d_in[6];
    const float* gamma = (const float*)d_in[7];
    float* out = (float*)d_out;

    float* Q  = (float*)d_ws;                          // B*N*KD  = 2 MB
    float* Km = Q  + (size_t)BATCH * NPIX * KD;        // B*KD*N  = 2 MB
    float* Vm = Km + (size_t)BATCH * KD * NPIX;        // B*N*OD  = 4 MB

    qkv_kernel<<<BATCH * (NPIX / 64), 256, 0, stream>>>(x, Wq, bq, Wk, bk, Wv, bv, Q, Km, Vm);
    attn_kernel<<<BATCH * NPIX, 256, 0, stream>>>(x, Q, Km, Vm, gamma, out);
}

// Round 4
// 670.126 us; speedup vs baseline: 1.3476x; 1.3476x over previous
//
#include <hip/hip_runtime.h>

#define BATCH 4
#define CCH   64
#define NPIX  4096
#define KD    32
#define OD    64
#define KK    409       // N / TOPK
#define EPSF  1e-10f
#define CAND_CAP 2048

__device__ __forceinline__ unsigned fkey(float f) {
    unsigned b = __float_as_uint(f);
    return b ^ ((b & 0x80000000u) ? 0xFFFFFFFFu : 0x80000000u);
}
__device__ __forceinline__ float unfkey(unsigned u) {
    unsigned b = (u & 0x80000000u) ? (u ^ 0x80000000u) : ~u;
    return __uint_as_float(b);
}

// ---------------------------------------------------------------------------
// Kernel A: per-pixel linear projections (1x1 convs).  (unchanged, ~17us)
// ---------------------------------------------------------------------------
__global__ __launch_bounds__(256) void qkv_kernel(
    const float* __restrict__ x,
    const float* __restrict__ Wq, const float* __restrict__ bq,
    const float* __restrict__ Wk, const float* __restrict__ bk,
    const float* __restrict__ Wv, const float* __restrict__ bv,
    float* __restrict__ Q, float* __restrict__ Km, float* __restrict__ Vm)
{
    __shared__ float xt[64][65];
    __shared__ float wq_s[KD * 64];
    __shared__ float wk_s[KD * 64];
    __shared__ float wv_s[OD * 64];
    __shared__ float bq_s[KD], bk_s[KD], bv_s[OD];

    int tid = threadIdx.x;
    int bx  = blockIdx.x;
    int b   = bx >> 6;
    int n0  = (bx & 63) << 6;

    for (int i = tid; i < KD * 64; i += 256) { wq_s[i] = Wq[i]; wk_s[i] = Wk[i]; }
    for (int i = tid; i < OD * 64; i += 256) wv_s[i] = Wv[i];
    if (tid < KD) { bq_s[tid] = bq[tid]; bk_s[tid] = bk[tid]; }
    if (tid < OD) bv_s[tid] = bv[tid];
    for (int i = tid; i < 64 * 64; i += 256) {
        int c = i >> 6, p = i & 63;
        xt[c][p] = x[((size_t)b * CCH + c) * NPIX + n0 + p];
    }
    __syncthreads();

    int px  = tid & 63;
    int grp = tid >> 6;
    int n   = n0 + px;

    if (grp == 0) {
        for (int o = 0; o < KD; ++o) {
            float acc = bq_s[o];
            #pragma unroll
            for (int c = 0; c < 64; ++c) acc += wq_s[o * 64 + c] * xt[c][px];
            Q[((size_t)b * NPIX + n) * KD + o] = acc;
        }
    } else if (grp == 1) {
        for (int o = 0; o < KD; ++o) {
            float acc = bk_s[o];
            #pragma unroll
            for (int c = 0; c < 64; ++c) acc += wk_s[o * 64 + c] * xt[c][px];
            Km[((size_t)b * KD + o) * NPIX + n] = acc;
        }
    } else {
        int obase = (grp - 2) * 32;
        for (int oo = 0; oo < 32; ++oo) {
            int o = obase + oo;
            float acc = bv_s[o];
            #pragma unroll
            for (int c = 0; c < 64; ++c) acc += wv_s[o * 64 + c] * xt[c][px];
            Vm[((size_t)b * NPIX + n) * OD + o] = acc;
        }
    }
}

// ---------------------------------------------------------------------------
// Kernel B: one block per output row i. float4 energy, key-radix with
// candidate compaction + wave-parallel bin find, ballot compaction, float4 PV.
// ---------------------------------------------------------------------------
__global__ __launch_bounds__(256) void attn_kernel(
    const float* __restrict__ x,  const float* __restrict__ Q,
    const float* __restrict__ Km, const float* __restrict__ Vm,
    const float* __restrict__ gamma, float* __restrict__ out)
{
    __shared__ unsigned ekey[NPIX];          // 16 KB: monotone keys of energies
    __shared__ unsigned cand[CAND_CAP];      // 8 KB: pass-1 candidate keys
    __shared__ unsigned hist[256];
    __shared__ int   sel_idx[KK];
    __shared__ float sel_w[KK];
    __shared__ float4 pvred[64];             // 1 KB
    __shared__ unsigned redk[4];
    __shared__ float  redf[4];
    __shared__ unsigned sh_b, sh_r, sh_nsel, sh_neq, sh_ncand, sh_mkey;

    int tid  = threadIdx.x;
    int lane = tid & 63, wv = tid >> 6;
    int bx   = blockIdx.x;
    int b    = bx >> 12;
    int i    = bx & (NPIX - 1);

    if (tid == 0) { sh_nsel = 0u; sh_neq = 0u; sh_ncand = 0u; }

    // q row is block-uniform -> scalar loads / SGPRs
    const float* qrow = Q + ((size_t)b * NPIX + i) * KD;
    float rq[KD];
    #pragma unroll
    for (int kd = 0; kd < KD; ++kd) rq[kd] = qrow[kd];

    // ---- energy row (float4) -> keys in LDS; running max on keys ----
    const float4* Kb4 = (const float4*)(Km + (size_t)b * KD * NPIX);
    unsigned lmaxk = 0u;
    #pragma unroll
    for (int g = 0; g < 4; ++g) {
        int q4 = tid + (g << 8);             // float4 index 0..1023
        float4 acc = make_float4(0.f, 0.f, 0.f, 0.f);
        #pragma unroll
        for (int kd = 0; kd < KD; ++kd) {
            float4 kv = Kb4[(kd << 10) + q4];
            acc.x = fmaf(rq[kd], kv.x, acc.x);
            acc.y = fmaf(rq[kd], kv.y, acc.y);
            acc.z = fmaf(rq[kd], kv.z, acc.z);
            acc.w = fmaf(rq[kd], kv.w, acc.w);
        }
        unsigned k0 = fkey(acc.x), k1 = fkey(acc.y), k2 = fkey(acc.z), k3 = fkey(acc.w);
        lmaxk = max(lmaxk, max(max(k0, k1), max(k2, k3)));
        *((uint4*)&ekey[q4 << 2]) = make_uint4(k0, k1, k2, k3);
    }
    #pragma unroll
    for (int off = 32; off; off >>= 1)
        lmaxk = max(lmaxk, (unsigned)__shfl_down((int)lmaxk, off, 64));
    if (lane == 0) redk[wv] = lmaxk;
    __syncthreads();                          // also publishes ekey
    if (tid == 0) sh_mkey = max(max(redk[0], redk[1]), max(redk[2], redk[3]));
    __syncthreads();
    float m = unfkey(sh_mkey);

    // ---- exact radix select (4 byte passes, candidates compacted after p0) ----
    unsigned prefix = 0u, kmask = 0u, r = KK;
    for (int pass = 0; pass < 4; ++pass) {
        int shift = 24 - (pass << 3);
        hist[tid] = 0u;
        __syncthreads();
        if (pass == 0) {
            for (int g = 0; g < 16; ++g) {
                unsigned u = ekey[tid + (g << 8)];
                atomicAdd(&hist[u >> 24], 1u);
            }
        } else {
            unsigned nc = sh_ncand;
            bool fb = (nc > CAND_CAP);
            int cnt = fb ? NPIX : (int)nc;
            const unsigned* src = fb ? ekey : cand;
            for (int t = tid; t < cnt; t += 256) {
                unsigned u = src[t];
                if ((u & kmask) == prefix) atomicAdd(&hist[(u >> shift) & 255u], 1u);
            }
        }
        __syncthreads();
        if (wv == 0) {
            uint4 h = *((const uint4*)&hist[lane << 2]);
            unsigned s3 = h.w, s2 = h.w + h.z, s1 = s2 + h.y, s0 = s1 + h.x;
            unsigned X = s0;
            #pragma unroll
            for (int off = 1; off < 64; off <<= 1) {
                unsigned v = (unsigned)__shfl_down((int)X, off, 64);
                if (lane + off < 64) X += v;
            }
            unsigned Xn = (unsigned)__shfl_down((int)X, 1, 64);
            if (lane == 63) Xn = 0u;
            unsigned S0 = X, S1 = Xn + s1, S2 = Xn + s2, S3 = Xn + s3, S4 = Xn;
            if (S0 >= r && S1 < r) { sh_b = (lane << 2) | 0; sh_r = r - S1; }
            if (S1 >= r && S2 < r) { sh_b = (lane << 2) | 1; sh_r = r - S2; }
            if (S2 >= r && S3 < r) { sh_b = (lane << 2) | 2; sh_r = r - S3; }
            if (S3 >= r && S4 < r) { sh_b = (lane << 2) | 3; sh_r = r - S4; }
        }
        __syncthreads();
        unsigned bsel = sh_b;
        r = sh_r;
        prefix |= bsel << shift;
        kmask  |= 0xFFu << shift;
        if (pass == 0) {
            for (int g = 0; g < 16; ++g) {
                unsigned u = ekey[tid + (g << 8)];
                bool c = (u >> 24) == bsel;
                unsigned long long msk = __ballot(c);
                if (msk) {
                    int leader = __ffsll(msk) - 1;
                    int base = 0;
                    if (lane == leader) base = (int)atomicAdd(&sh_ncand, (unsigned)__popcll(msk));
                    base = __shfl(base, leader, 64);
                    if (c) {
                        unsigned pos = (unsigned)base + (unsigned)__popcll(msk & ((1ull << lane) - 1ull));
                        if (pos < CAND_CAP) cand[pos] = u;
                    }
                }
            }
            __syncthreads();
        }
    }
    unsigned tu = prefix;      // exact key of the KK-th largest; r equal keys to keep

    // ---- selection: compact (idx, weight) with per-wave ballots ----
    float lsum = 0.f;
    for (int g = 0; g < 16; ++g) {
        int j = tid + (g << 8);
        unsigned u = ekey[j];
        bool sel = (u > tu);
        if (u == tu) {
            unsigned p = atomicAdd(&sh_neq, 1u);
            sel = (p < r);
        }
        unsigned long long msk = __ballot(sel);
        if (msk) {
            int leader = __ffsll(msk) - 1;
            int base = 0;
            if (lane == leader) base = (int)atomicAdd(&sh_nsel, (unsigned)__popcll(msk));
            base = __shfl(base, leader, 64);
            if (sel) {
                int pos = base + (int)__popcll(msk & ((1ull << lane) - 1ull));
                float w = __expf(unfkey(u) - m);
                sel_idx[pos] = j;
                sel_w[pos]   = w;
                lsum += w;
            }
        }
    }
    #pragma unroll
    for (int off = 32; off; off >>= 1) lsum += __shfl_down(lsum, off, 64);
    if (lane == 0) redf[wv] = lsum;
    __syncthreads();                          // sel lists + partial sums ready
    float denom = (redf[0] + redf[1] + redf[2] + redf[3]) + EPSF;
    int nsel = (int)sh_nsel;                  // == KK

    // ---- PV gather: 4 entries x 16 lanes x float4 per wave ----
    int eslot = lane >> 4, vq = lane & 15;
    const float4* Vb4 = (const float4*)(Vm + (size_t)b * NPIX * OD);
    float4 acc = make_float4(0.f, 0.f, 0.f, 0.f);
    for (int s0 = (wv << 2); s0 < nsel; s0 += 16) {
        int s = s0 + eslot;
        if (s < nsel) {
            float w = sel_w[s];
            int j   = sel_idx[s];
            float4 v4 = Vb4[(j << 4) + vq];
            acc.x = fmaf(w, v4.x, acc.x);
            acc.y = fmaf(w, v4.y, acc.y);
            acc.z = fmaf(w, v4.z, acc.z);
            acc.w = fmaf(w, v4.w, acc.w);
        }
    }
    #pragma unroll
    for (int off = 16; off <= 32; off <<= 1) {
        acc.x += __shfl_xor(acc.x, off, 64);
        acc.y += __shfl_xor(acc.y, off, 64);
        acc.z += __shfl_xor(acc.z, off, 64);
        acc.w += __shfl_xor(acc.w, off, 64);
    }
    if (lane < 16) pvred[(wv << 4) + vq] = acc;
    __syncthreads();
    if (tid < 64) {
        const float* pvf = (const float*)pvred;
        float o = pvf[tid] + pvf[64 + tid] + pvf[128 + tid] + pvf[192 + tid];
        float scale = gamma[0] / denom;
        size_t oi = ((size_t)b * CCH + tid) * NPIX + i;
        out[oi] = fmaf(scale, o, x[oi]);
    }
}

extern "C" void kernel_launch(void* const* d_in, const int* in_sizes, int n_in,
                              void* d_out, int out_size, void* d_ws, size_t ws_size,
                              hipStream_t stream) {
    const float* x     = (const float*)d_in[0];
    const float* Wq    = (const float*)d_in[1];
    const float* bq    = (const float*)d_in[2];
    const float* Wk    = (const float*)d_in[3];
    const float* bk    = (const float*)d_in[4];
    const float* Wv    = (const float*)d_in[5];
    const float* bv    = (const float*)d_in[6];
    const float* gamma = (const float*)d_in[7];
    float* out = (float*)d_out;

    float* Q  = (float*)d_ws;
    float* Km = Q  + (size_t)BATCH * NPIX * KD;
    float* Vm = Km + (size_t)BATCH * KD * NPIX;

    qkv_kernel<<<BATCH * (NPIX / 64), 256, 0, stream>>>(x, Wq, bq, Wk, bk, Wv, bv, Q, Km, Vm);
    attn_kernel<<<BATCH * NPIX, 256, 0, stream>>>(x, Q, Km, Vm, gamma, out);
}